// Round 5
// baseline (1072.127 us; speedup 1.0000x reference)
//
#include <hip/hip_runtime.h>
#include <hip/hip_bf16.h>
#include <stdint.h>

typedef __hip_bfloat16 bf16;
typedef __attribute__((ext_vector_type(8))) short bf16x8;
typedef __attribute__((ext_vector_type(4))) float f32x4;

#define VOCABN 100000
#define EDIM 128
#define BN 16
#define SN 2048
#define GRID 256
#define TPB 512
#define NWAVE (GRID * 8)   // 2048 global waves

// ws float offsets (end = 3,740,672 floats = 14.96 MB; 17.07 MB proven available)
#define CTR_OFF 0        // 16 u32 barrier counters (memset to 0 each launch)
#define PS_OFF  64       // 512  (psum[16][32])
#define U0_OFF  576      // 2048
#define U1_OFF  2624     // 2048
#define U2_OFF  4672     // 2048
#define PBV_OFF 6720     // 1200
#define PBI_OFF 7920     // 1200
#define DT_OFF  16384    // 1,600,000 (D^T [100000][16])
#define WT_OFF  1616384  // 1,600,000 (wt  [100000][16])
#define DUP_OFF 3216384  // 256*2048 du partials

// ---------- threefry2x32 (JAX partitionable) ----------
__host__ __device__ inline void tf2x32(uint32_t k0, uint32_t k1,
                                       uint32_t x0, uint32_t x1,
                                       uint32_t* o0, uint32_t* o1) {
  const uint32_t rotA[4] = {13u, 15u, 26u, 6u};
  const uint32_t rotB[4] = {17u, 29u, 16u, 24u};
  uint32_t ks0 = k0, ks1 = k1, ks2 = k0 ^ k1 ^ 0x1BD11BDAu;
  x0 += ks0; x1 += ks1;
#pragma unroll
  for (int g = 0; g < 5; ++g) {
    const uint32_t* r = (g & 1) ? rotB : rotA;
#pragma unroll
    for (int i = 0; i < 4; ++i) {
      x0 += x1;
      x1 = (x1 << r[i]) | (x1 >> (32u - r[i]));
      x1 ^= x0;
    }
    uint32_t a0 = (g % 3 == 0) ? ks1 : ((g % 3 == 1) ? ks2 : ks0);
    uint32_t a1 = (g % 3 == 0) ? ks2 : ((g % 3 == 1) ? ks0 : ks1);
    x0 += a0;
    x1 += a1 + (uint32_t)(g + 1);
  }
  *o0 = x0; *o1 = x1;
}

__device__ inline uint16_t f2bu(float f) {
  bf16 h = __float2bfloat16(f);
  uint16_t u; __builtin_memcpy(&u, &h, 2); return u;
}
__device__ inline float gumbel(uint32_t ka, uint32_t kb, uint32_t flat) {
  uint32_t o0, o1;
  tf2x32(ka, kb, 0u, flat, &o0, &o1);
  uint32_t bits = o0 ^ o1;
  float u0 = __uint_as_float((bits >> 9) | 0x3f800000u) - 1.0f;
  float uu = fmaxf(1e-10f, u0 + 1e-10f);
  return -logf(-logf(uu));
}

// ---------- grid barrier: device-scope, counter per barrier ----------
__device__ inline void gbar(uint32_t* ctr) {
  __syncthreads();
  if (threadIdx.x == 0) {
    __threadfence();  // agent release: local-L2 writeback (cross-XCD visibility)
    __hip_atomic_fetch_add(ctr, 1u, __ATOMIC_RELEASE, __HIP_MEMORY_SCOPE_AGENT);
    while (__hip_atomic_load(ctr, __ATOMIC_ACQUIRE, __HIP_MEMORY_SCOPE_AGENT)
           < (uint32_t)GRID)
      __builtin_amdgcn_s_sleep(2);
    __threadfence();  // agent acquire: invalidate stale local caches
  }
  __syncthreads();
}

// ---------- D-pass: Dt[v][b] = Ct[v] . u[b]  (MFMA hi/lo split, R3-verified) ----------
__device__ void phase_D(const float* __restrict__ Ct, const float* ub,
                        float* __restrict__ Dt, int gw) {
  const int lane = threadIdx.x & 63;
  const int n = lane & 15, q = lane >> 4;
  bf16x8 Bhi[4], Blo[4];
#pragma unroll
  for (int kk = 0; kk < 4; ++kk) {
    const float* up = ub + n * EDIM + kk * 32 + q * 8;
    float4 x0 = *(const float4*)up, x1 = *(const float4*)(up + 4);
    float xs[8] = {x0.x, x0.y, x0.z, x0.w, x1.x, x1.y, x1.z, x1.w};
#pragma unroll
    for (int i = 0; i < 8; ++i) {
      uint16_t hb = f2bu(xs[i]);
      float hf = __uint_as_float((uint32_t)hb << 16);
      Bhi[kk][i] = (short)hb;
      Blo[kk][i] = (short)f2bu(xs[i] - hf);
    }
  }
  for (int t = gw; t < VOCABN / 16; t += NWAVE) {
    const int v0 = t * 16;
    f32x4 acc = {0.f, 0.f, 0.f, 0.f};
#pragma unroll
    for (int kk = 0; kk < 4; ++kk) {
      const float* ap = Ct + (size_t)(v0 + n) * EDIM + kk * 32 + q * 8;
      float4 a0 = *(const float4*)ap, a1 = *(const float4*)(ap + 4);
      bf16x8 A;
      A[0] = (short)f2bu(a0.x); A[1] = (short)f2bu(a0.y);
      A[2] = (short)f2bu(a0.z); A[3] = (short)f2bu(a0.w);
      A[4] = (short)f2bu(a1.x); A[5] = (short)f2bu(a1.y);
      A[6] = (short)f2bu(a1.z); A[7] = (short)f2bu(a1.w);
      acc = __builtin_amdgcn_mfma_f32_16x16x32_bf16(A, Bhi[kk], acc, 0, 0, 0);
      acc = __builtin_amdgcn_mfma_f32_16x16x32_bf16(A, Blo[kk], acc, 0, 0, 0);
    }
#pragma unroll
    for (int j = 0; j < 4; ++j)
      Dt[(size_t)(v0 + q * 4 + j) * 16 + n] = acc[j];
  }
}

// ---------- heads unit (1 wave = 1 chunk-unit) ----------
__device__ void do_heads(int unit, const float* h_lds,
                         const float* __restrict__ W1w, const float* __restrict__ W1b,
                         const float* __restrict__ W3w, const float* __restrict__ W3b,
                         const float* __restrict__ W4w, const float* __restrict__ W4b,
                         float* __restrict__ out, float* __restrict__ pbv,
                         int* __restrict__ pbi,
                         uint32_t k0a, uint32_t k0b, uint32_t k1a, uint32_t k1b,
                         uint32_t k2a, uint32_t k2b) {
  const int lane = threadIdx.x & 63;
  int head, b2, base, cnt, chunk, N;
  const float *W, *bias; size_t lg; uint32_t ka, kb;
  if (unit < 400)      { head = 1; b2 = unit / 25; chunk = unit % 25; base = chunk * 160; cnt = 160;
                         W = W3w; bias = W3b; N = 4000; lg = 64;     ka = k1a; kb = k1b; }
  else if (unit < 416) { head = 2; b2 = unit - 400; chunk = 0; base = 0; cnt = 200;
                         W = W4w; bias = W4b; N = 200;  lg = 128064; ka = k2a; kb = k2b; }
  else                 { head = 0; b2 = unit - 416; chunk = 0; base = 0; cnt = 2;
                         W = W1w; bias = W1b; N = 2;    lg = 0;      ka = k0a; kb = k0b; }
  const float4* hb4 = (const float4*)(h_lds + b2 * EDIM);
  float best = -INFINITY; int bi = 0x7FFFFFFF;
  for (int c = base + lane; c < base + cnt; c += 64) {
    const float4* wr = (const float4*)(W + (size_t)c * EDIM);
    float acc = bias[c];
#pragma unroll
    for (int i = 0; i < 32; ++i) {
      float4 w4 = wr[i], h4 = hb4[i];
      acc += w4.x * h4.x + w4.y * h4.y + w4.z * h4.z + w4.w * h4.w;
    }
    out[lg + (size_t)b2 * N + c] = acc;
    float g = acc + gumbel(ka, kb, (uint32_t)(b2 * N + c));
    if (g > best || (g == best && c < bi)) { best = g; bi = c; }
  }
#pragma unroll
  for (int off = 32; off > 0; off >>= 1) {
    float ov = __shfl_xor(best, off, 64);
    int oi = __shfl_xor(bi, off, 64);
    if (ov > best || (ov == best && oi < bi)) { best = ov; bi = oi; }
  }
  if (lane == 0) {
    pbv[(head * 16 + b2) * 25 + chunk] = best;
    pbi[(head * 16 + b2) * 25 + chunk] = bi;
  }
}

// ---------- lscat: l = sum_m Dt[tok][b]; exp -> wt atomics + psum ----------
__device__ void do_lscat(const int* __restrict__ story, const float* __restrict__ Dt,
                         float* __restrict__ wt, float* __restrict__ ps) {
  const int gt = blockIdx.x * TPB + threadIdx.x;   // blocks 0..63 -> gt < 32768
  const int lane = threadIdx.x & 63;
  const int b = gt >> 11, s = gt & 2047;
  int4 tk = ((const int4*)story)[b * SN + s];
  float l = Dt[(size_t)tk.x * 16 + b] + Dt[(size_t)tk.y * 16 + b]
          + Dt[(size_t)tk.z * 16 + b] + Dt[(size_t)tk.w * 16 + b];
  float e = expf(l);
  atomicAdd(&wt[(size_t)tk.x * 16 + b], e);
  atomicAdd(&wt[(size_t)tk.y * 16 + b], e);
  atomicAdd(&wt[(size_t)tk.z * 16 + b], e);
  atomicAdd(&wt[(size_t)tk.w * 16 + b], e);
  float sum = e;
#pragma unroll
  for (int off = 32; off > 0; off >>= 1) sum += __shfl_xor(sum, off, 64);
  if (lane == 0) ps[b * 32 + (s >> 6)] = sum;
}

// ---------- du-pass: per-block partial of sum_v wt[v][b]*Ct[v][:] ----------
__device__ void phase_du(const float* __restrict__ Ct, const float* __restrict__ wt,
                         float* __restrict__ dup, float* pool) {
  const int tid = threadIdx.x, bid = blockIdx.x;
  const int lane = tid & 63, w = tid >> 6;
  float2 acc[16];
#pragma unroll
  for (int b = 0; b < 16; ++b) acc[b] = make_float2(0.f, 0.f);
  int r0 = bid * 392 + w * 49;
  int rn = VOCABN - r0;
  rn = rn < 0 ? 0 : (rn > 49 ? 49 : rn);
  for (int r = 0; r < rn; ++r) {
    const int v = r0 + r;
    float2 cc = *(const float2*)(Ct + (size_t)v * EDIM + lane * 2);
    const float4* wp = (const float4*)(wt + (size_t)v * 16);
    float4 w0 = wp[0], w1 = wp[1], w2 = wp[2], w3 = wp[3];
    float wv[16] = {w0.x, w0.y, w0.z, w0.w, w1.x, w1.y, w1.z, w1.w,
                    w2.x, w2.y, w2.z, w2.w, w3.x, w3.y, w3.z, w3.w};
#pragma unroll
    for (int b = 0; b < 16; ++b) {
      acc[b].x += wv[b] * cc.x;
      acc[b].y += wv[b] * cc.y;
    }
  }
  // cross-wave tree reduce in LDS (stride 17 float2 per lane: conflict-free)
  float2* L = (float2*)pool;
  if (w >= 4) {
#pragma unroll
    for (int b = 0; b < 16; ++b) L[(w - 4) * 1088 + lane * 17 + b] = acc[b];
  }
  __syncthreads();
  if (w < 4) {
#pragma unroll
    for (int b = 0; b < 16; ++b) {
      float2 v = L[w * 1088 + lane * 17 + b];
      acc[b].x += v.x; acc[b].y += v.y;
    }
  }
  __syncthreads();
  if (w == 2 || w == 3) {
#pragma unroll
    for (int b = 0; b < 16; ++b) L[(w - 2) * 1088 + lane * 17 + b] = acc[b];
  }
  __syncthreads();
  if (w < 2) {
#pragma unroll
    for (int b = 0; b < 16; ++b) {
      float2 v = L[w * 1088 + lane * 17 + b];
      acc[b].x += v.x; acc[b].y += v.y;
    }
  }
  __syncthreads();
  if (w == 1) {
#pragma unroll
    for (int b = 0; b < 16; ++b) L[lane * 17 + b] = acc[b];
  }
  __syncthreads();
  if (w == 0) {
#pragma unroll
    for (int b = 0; b < 16; ++b) {
      float2 v = L[lane * 17 + b];
      acc[b].x += v.x; acc[b].y += v.y;
      *(float2*)(dup + (size_t)bid * 2048 + b * EDIM + lane * 2) = acc[b];
    }
  }
}

// ---------- red: u_next[o] = u_prev[o] + (sum_p dup[p][o]) / S_b ----------
__device__ void phase_red(const float* __restrict__ dup, const float* __restrict__ ps,
                          const float* __restrict__ up, float* __restrict__ un) {
  const int lane = threadIdx.x & 63, w = threadIdx.x >> 6;
  const int o = blockIdx.x * 8 + w;           // 0..2047
  float t = dup[(size_t)lane * 2048 + o]
          + dup[(size_t)(lane + 64) * 2048 + o]
          + dup[(size_t)(lane + 128) * 2048 + o]
          + dup[(size_t)(lane + 192) * 2048 + o];
#pragma unroll
  for (int off = 32; off > 0; off >>= 1) t += __shfl_xor(t, off, 64);
  const int b = o >> 7;
  float sv = (lane < 32) ? ps[b * 32 + lane] : 0.f;
#pragma unroll
  for (int off = 32; off > 0; off >>= 1) sv += __shfl_xor(sv, off, 64);
  if (lane == 0) un[o] = up[o] + t / sv;
}

// ---------- the mega-kernel ----------
__global__ void __launch_bounds__(TPB, 2)
k_mega(const int* __restrict__ story, const int* __restrict__ lengths,
       const float* __restrict__ hidden, const float* __restrict__ C,
       const float* __restrict__ Wm, const float* __restrict__ Wb,
       const float* __restrict__ W1w, const float* __restrict__ W1b,
       const float* __restrict__ W3w, const float* __restrict__ W3b,
       const float* __restrict__ W4w, const float* __restrict__ W4b,
       float* __restrict__ out, float* __restrict__ ws,
       uint32_t k0a, uint32_t k0b, uint32_t k1a, uint32_t k1b,
       uint32_t k2a, uint32_t k2b) {
  const int bid = blockIdx.x, tid = threadIdx.x;
  const int w = tid >> 6;
  const int gw = bid * 8 + w;
  __shared__ __align__(16) float pool[9216];   // 36 KB: h (P0/P1) / du-tree (P3,P7)

  uint32_t* ctr = (uint32_t*)(ws + CTR_OFF);
  float* ps  = ws + PS_OFF;
  float* u0g = ws + U0_OFF;
  float* u1g = ws + U1_OFF;
  float* u2g = ws + U2_OFF;
  float* pbv = ws + PBV_OFF;
  int*   pbi = (int*)(ws + PBI_OFF);
  float* Dt  = ws + DT_OFF;
  float* wt  = ws + WT_OFF;
  float* dup = ws + DUP_OFF;
  const float* C0 = C;
  const float* C1 = C + (size_t)1 * VOCABN * EDIM;
  const float* C2 = C + (size_t)2 * VOCABN * EDIM;

  // --- P0: every block computes h = hidden@Wm^T+Wb into LDS (identical copies) ---
  for (int i = tid; i < 2048; i += TPB) {
    int b = i >> 7, j = i & 127;
    const float4* wr = (const float4*)(Wm + (size_t)j * EDIM);
    const float4* hr = (const float4*)(hidden + (size_t)b * EDIM);
    float acc = Wb[j];
#pragma unroll
    for (int q = 0; q < 32; ++q) {
      float4 w4 = wr[q], h4 = hr[q];
      acc += w4.x * h4.x + w4.y * h4.y + w4.z * h4.z + w4.w * h4.w;
    }
    pool[i] = acc;
  }
  __syncthreads();
  if (tid < 8) u0g[bid * 8 + tid] = pool[bid * 8 + tid];  // stash slice for P4

  // --- P1: zero wt + heads + D0 = C0 . u0 ---
  for (int i = bid * TPB + tid; i < VOCABN * 16; i += GRID * TPB) wt[i] = 0.f;
  if (gw < 432)
    do_heads(gw, pool, W1w, W1b, W3w, W3b, W4w, W4b, out, pbv, pbi,
             k0a, k0b, k1a, k1b, k2a, k2b);
  phase_D(C0, pool, Dt, gw);
  gbar(ctr + 0);

  // --- P2: lscat hop0 (blocks 0..63) + one-hots (blocks 64..255) ---
  if (bid < 64) {
    do_lscat(story, Dt, wt, ps);
  } else {
    int g = (bid - 64) * TPB + tid;
    if (g < 67232) {
      int head, b2, c; size_t off; int nch;
      if (g < 64000)      { head = 1; b2 = g / 4000; c = g % 4000; off = 64064 + g;          nch = 25; }
      else if (g < 67200) { int gg = g - 64000; head = 2; b2 = gg / 200; c = gg % 200; off = 131264 + gg; nch = 1; }
      else                { int gg = g - 67200; head = 0; b2 = gg >> 1; c = gg & 1;   off = 32 + gg;     nch = 1; }
      float bv = -INFINITY; int bi2 = 0x7FFFFFFF;
      for (int ch = 0; ch < nch; ++ch) {
        float v = pbv[(head * 16 + b2) * 25 + ch];
        int i2 = pbi[(head * 16 + b2) * 25 + ch];
        if (v > bv || (v == bv && i2 < bi2)) { bv = v; bi2 = i2; }
      }
      out[off] = (c == bi2) ? 1.0f : 0.0f;
    }
  }
  gbar(ctr + 1);

  // --- P3: du0 partials over C1 ---
  phase_du(C1, wt, dup, pool);
  gbar(ctr + 2);

  // --- P4: u1 = u0 + du0/S0 ; re-zero wt ---
  phase_red(dup, ps, u0g, u1g);
  for (int i = bid * TPB + tid; i < VOCABN * 16; i += GRID * TPB) wt[i] = 0.f;
  gbar(ctr + 3);

  // --- P5: D1 = C1 . u1 ---
  phase_D(C1, u1g, Dt, gw);
  gbar(ctr + 4);

  // --- P6: lscat hop1 ---
  if (bid < 64) do_lscat(story, Dt, wt, ps);
  gbar(ctr + 5);

  // --- P7: du1 partials over C2 ---
  phase_du(C2, wt, dup, pool);
  gbar(ctr + 6);

  // --- P8: u2 = u1 + du1/S1 ---
  phase_red(dup, ps, u1g, u2g);
  gbar(ctr + 7);

  // --- P9: D2 = C2 . u2 ---
  phase_D(C2, u2g, Dt, gw);
  gbar(ctr + 8);

  // --- P10: final logits -> masked sigmoid ---
  {
    const int gt = bid * TPB + tid;
    if (gt < 32768) {
      const int b = gt >> 11, s = gt & 2047;
      int4 tk = ((const int4*)story)[b * SN + s];
      float l = Dt[(size_t)tk.x * 16 + b] + Dt[(size_t)tk.y * 16 + b]
              + Dt[(size_t)tk.z * 16 + b] + Dt[(size_t)tk.w * 16 + b];
      int len = lengths[b];
      out[134464 + (size_t)b * SN + s] = (s < len) ? 1.0f / (1.0f + expf(-l)) : 0.0f;
    }
  }
}

extern "C" void kernel_launch(void* const* d_in, const int* in_sizes, int n_in,
                              void* d_out, int out_size, void* d_ws, size_t ws_size,
                              hipStream_t stream) {
  const int *story = nullptr, *lengths = nullptr;
  const float *hidden = nullptr, *C = nullptr, *Wm = nullptr, *Wb = nullptr,
              *W1w = nullptr, *W1b = nullptr, *W3w = nullptr, *W3b = nullptr,
              *W4w = nullptr, *W4b = nullptr;
  for (int i = 0; i < n_in; ++i) {
    switch (in_sizes[i]) {
      case 16 * 2048 * 4:    story   = (const int*)d_in[i]; break;
      case 16:               lengths = (const int*)d_in[i]; break;
      case 16 * 128:         hidden  = (const float*)d_in[i]; break;
      case 4 * 100000 * 128: C       = (const float*)d_in[i]; break;
      case 128 * 128:        Wm      = (const float*)d_in[i]; break;
      case 128:              Wb      = (const float*)d_in[i]; break;
      case 2 * 128:          W1w     = (const float*)d_in[i]; break;
      case 2:                W1b     = (const float*)d_in[i]; break;
      case 4000 * 128:       W3w     = (const float*)d_in[i]; break;
      case 4000:             W3b     = (const float*)d_in[i]; break;
      case 200 * 128:        W4w     = (const float*)d_in[i]; break;
      case 200:              W4b     = (const float*)d_in[i]; break;
      default: break;
    }
  }
  float* out = (float*)d_out;
  float* ws  = (float*)d_ws;

  uint32_t k0a, k0b, k1a, k1b, k2a, k2b;
  tf2x32(0u, 42u, 0u, 0u, &k0a, &k0b);
  tf2x32(0u, 42u, 0u, 1u, &k1a, &k1b);
  tf2x32(0u, 42u, 0u, 2u, &k2a, &k2b);

  hipMemsetAsync(d_ws, 0, 64, stream);   // zero the 9 barrier counters

  // Cooperative launch: runtime-guaranteed co-residency for the grid barrier
  // (guide §1: supported by the grading harness; removes the deadlock risk of
  // manual capacity arithmetic).
  void* args[] = {(void*)&story, (void*)&lengths, (void*)&hidden, (void*)&C,
                  (void*)&Wm, (void*)&Wb, (void*)&W1w, (void*)&W1b,
                  (void*)&W3w, (void*)&W3b, (void*)&W4w, (void*)&W4b,
                  (void*)&out, (void*)&ws,
                  (void*)&k0a, (void*)&k0b, (void*)&k1a, (void*)&k1b,
                  (void*)&k2a, (void*)&k2b};
  hipLaunchCooperativeKernel((const void*)k_mega, dim3(GRID), dim3(TPB),
                             args, 0, stream);
}

// Round 7
// 408.257 us; speedup vs baseline: 2.6261x; 2.6261x over previous
//
#include <hip/hip_runtime.h>
#include <hip/hip_bf16.h>
#include <stdint.h>

typedef __hip_bfloat16 bf16;
typedef __attribute__((ext_vector_type(8))) short bf16x8;
typedef __attribute__((ext_vector_type(4))) float f32x4;

#define VOCABN 100000
#define EDIM 128
#define BN 16
#define SN 2048

#define NB_D    782      // k_D blocks; 4 waves each -> 3128 waves; 2 tiles/wave
#define NT      6250     // 16-row tiles in vocab
#define NB_DU   512      // k_du blocks
#define ROWS_PB 196      // rows per k_du block (512*196 = 100352 >= 100000)

// ws float offsets (end = 4,264,960 floats = 17.06 MB -- R3-proven size)
#define U0_OFF   0        // 2048
#define U1_OFF   2048     // 2048
#define U2_OFF   4096     // 2048
#define PS_OFF   6144     // 512  (psum[16][32], per-wave sums)
#define PBV_OFF  6656     // 1200
#define PBI_OFF  7856     // 1200
#define DT_OFF   16384    // 1,600,000 (D^T [100000][16])
#define WT_OFF   1616384  // 1,600,000 (wt  [100000][16])
#define DUP_OFF  3216384  // 512*2048 = 1,048,576 (du partials)

// ---------- threefry2x32 (JAX partitionable) ----------
__host__ __device__ inline void tf2x32(uint32_t k0, uint32_t k1,
                                       uint32_t x0, uint32_t x1,
                                       uint32_t* o0, uint32_t* o1) {
  const uint32_t rotA[4] = {13u, 15u, 26u, 6u};
  const uint32_t rotB[4] = {17u, 29u, 16u, 24u};
  uint32_t ks0 = k0, ks1 = k1, ks2 = k0 ^ k1 ^ 0x1BD11BDAu;
  x0 += ks0; x1 += ks1;
#pragma unroll
  for (int g = 0; g < 5; ++g) {
    const uint32_t* r = (g & 1) ? rotB : rotA;
#pragma unroll
    for (int i = 0; i < 4; ++i) {
      x0 += x1;
      x1 = (x1 << r[i]) | (x1 >> (32u - r[i]));
      x1 ^= x0;
    }
    uint32_t a0 = (g % 3 == 0) ? ks1 : ((g % 3 == 1) ? ks2 : ks0);
    uint32_t a1 = (g % 3 == 0) ? ks2 : ((g % 3 == 1) ? ks0 : ks1);
    x0 += a0;
    x1 += a1 + (uint32_t)(g + 1);
  }
  *o0 = x0; *o1 = x1;
}

__device__ inline uint16_t f2bu(float f) {
  bf16 h = __float2bfloat16(f);
  uint16_t u; __builtin_memcpy(&u, &h, 2); return u;
}
__device__ inline float gumbel(uint32_t ka, uint32_t kb, uint32_t flat) {
  uint32_t o0, o1;
  tf2x32(ka, kb, 0u, flat, &o0, &o1);
  uint32_t bits = o0 ^ o1;
  float u0 = __uint_as_float((bits >> 9) | 0x3f800000u) - 1.0f;
  float uu = fmaxf(1e-10f, u0 + 1e-10f);
  return -logf(-logf(uu));
}

// ---------- heads: in-block h = hidden@Wm^T+Wb; logits; gumbel-argmax partials ----------
// 16 designated blocks (head1, chunk0) persist h as u0 for the memory hops.
__global__ void k_heads(const float* __restrict__ hidden,
                        const float* __restrict__ Wm, const float* __restrict__ Wb,
                        const float* __restrict__ W1w, const float* __restrict__ W1b,
                        const float* __restrict__ W3w, const float* __restrict__ W3b,
                        const float* __restrict__ W4w, const float* __restrict__ W4b,
                        float* __restrict__ out, float* __restrict__ pbv,
                        int* __restrict__ pbi, float* __restrict__ u0,
                        uint32_t k0a, uint32_t k0b, uint32_t k1a, uint32_t k1b,
                        uint32_t k2a, uint32_t k2b) {
  int bid = blockIdx.x, tid = threadIdx.x;
  __shared__ float hb[EDIM];
  __shared__ float sv[256];
  __shared__ int si[256];
  int head, b2, base, cnt, chunk, N;
  const float *W, *bias; size_t lg_off; uint32_t ka, kb;
  if (bid < 400)      { head = 1; b2 = bid / 25; chunk = bid % 25; base = chunk * 160; cnt = 160;
                        W = W3w; bias = W3b; N = 4000; lg_off = 64;     ka = k1a; kb = k1b; }
  else if (bid < 416) { head = 2; b2 = bid - 400; chunk = 0; base = 0; cnt = 200;
                        W = W4w; bias = W4b; N = 200;  lg_off = 128064; ka = k2a; kb = k2b; }
  else                { head = 0; b2 = bid - 416; chunk = 0; base = 0; cnt = 2;
                        W = W1w; bias = W1b; N = 2;    lg_off = 0;      ka = k0a; kb = k0b; }
  if (tid < 128) {
    const float4* wr = (const float4*)(Wm + (size_t)tid * EDIM);
    const float4* hr = (const float4*)(hidden + (size_t)b2 * EDIM);
    float acc = Wb[tid];
#pragma unroll
    for (int i = 0; i < 32; ++i) {
      float4 w4 = wr[i], h4 = hr[i];
      acc += w4.x * h4.x + w4.y * h4.y + w4.z * h4.z + w4.w * h4.w;
    }
    hb[tid] = acc;
    if (bid < 400 && (bid % 25) == 0) u0[b2 * EDIM + tid] = acc;
  }
  __syncthreads();
  float best = -INFINITY; int bi = 0x7FFFFFFF;
  if (tid < cnt) {
    int c = base + tid;
    const float4* wr = (const float4*)(W + (size_t)c * EDIM);
    const float4* hb4 = (const float4*)hb;
    float acc = bias[c];
#pragma unroll
    for (int i = 0; i < 32; ++i) {
      float4 w4 = wr[i], h4 = hb4[i];
      acc += w4.x * h4.x + w4.y * h4.y + w4.z * h4.z + w4.w * h4.w;
    }
    out[lg_off + (size_t)b2 * N + c] = acc;
    best = acc + gumbel(ka, kb, (uint32_t)(b2 * N + c));
    bi = c;
  }
  sv[tid] = best; si[tid] = bi;
  __syncthreads();
  for (int s2 = 128; s2 > 0; s2 >>= 1) {
    if (tid < s2) {
      float ov = sv[tid + s2]; int oi = si[tid + s2];
      if (ov > sv[tid] || (ov == sv[tid] && oi < si[tid])) { sv[tid] = ov; si[tid] = oi; }
    }
    __syncthreads();
  }
  if (tid == 0) {
    pbv[(head * 16 + b2) * 25 + chunk] = sv[0];
    pbi[(head * 16 + b2) * 25 + chunk] = si[0];
  }
}

// ---------- k_D (MFMA, depth-2 tile pipeline): Dt[v][b] = Ct[v] . u[b] ----------
// Wave owns tiles gw and gw+3128; all 16 dwordx4 loads issue before compute.
__global__ void __launch_bounds__(256, 3) k_D(const float* __restrict__ Ct,
                                              const float* __restrict__ ub,
                                              float* __restrict__ Dt,
                                              float* __restrict__ wtz) {
  const int tid = threadIdx.x, bid = blockIdx.x;
  const int lane = tid & 63, w = tid >> 6;
  const int n = lane & 15, q = lane >> 4;
  if (wtz) {
    for (int i = bid * 256 + tid; i < VOCABN * 16; i += NB_D * 256) wtz[i] = 0.f;
  }
  // u fragments: hi + residual-lo bf16 pair (R3-verified numerics)
  bf16x8 Bhi[4], Blo[4];
#pragma unroll
  for (int kk = 0; kk < 4; ++kk) {
    const float* up = ub + n * EDIM + kk * 32 + q * 8;
    float4 x0 = *(const float4*)up, x1 = *(const float4*)(up + 4);
    float xs[8] = {x0.x, x0.y, x0.z, x0.w, x1.x, x1.y, x1.z, x1.w};
#pragma unroll
    for (int i = 0; i < 8; ++i) {
      uint16_t hbv = f2bu(xs[i]);
      float hf = __uint_as_float((uint32_t)hbv << 16);
      Bhi[kk][i] = (short)hbv;
      Blo[kk][i] = (short)f2bu(xs[i] - hf);
    }
  }
  const int gw = bid * 4 + w;
  const int tA = gw, tB = gw + NB_D * 4;     // NB_D*4 = 3128
  const bool hB = (tB < NT);
  float4 a[8], b[8];
  {
    const float* ap = Ct + (size_t)(tA * 16 + n) * EDIM + q * 8;
#pragma unroll
    for (int kk = 0; kk < 4; ++kk) {
      a[2 * kk]     = *(const float4*)(ap + kk * 32);
      a[2 * kk + 1] = *(const float4*)(ap + kk * 32 + 4);
    }
  }
  if (hB) {
    const float* bp = Ct + (size_t)(tB * 16 + n) * EDIM + q * 8;
#pragma unroll
    for (int kk = 0; kk < 4; ++kk) {
      b[2 * kk]     = *(const float4*)(bp + kk * 32);
      b[2 * kk + 1] = *(const float4*)(bp + kk * 32 + 4);
    }
  }
  {
    f32x4 acc = {0.f, 0.f, 0.f, 0.f};
#pragma unroll
    for (int kk = 0; kk < 4; ++kk) {
      float4 a0 = a[2 * kk], a1 = a[2 * kk + 1];
      bf16x8 A;
      A[0] = (short)f2bu(a0.x); A[1] = (short)f2bu(a0.y);
      A[2] = (short)f2bu(a0.z); A[3] = (short)f2bu(a0.w);
      A[4] = (short)f2bu(a1.x); A[5] = (short)f2bu(a1.y);
      A[6] = (short)f2bu(a1.z); A[7] = (short)f2bu(a1.w);
      acc = __builtin_amdgcn_mfma_f32_16x16x32_bf16(A, Bhi[kk], acc, 0, 0, 0);
      acc = __builtin_amdgcn_mfma_f32_16x16x32_bf16(A, Blo[kk], acc, 0, 0, 0);
    }
#pragma unroll
    for (int j = 0; j < 4; ++j)
      Dt[(size_t)(tA * 16 + q * 4 + j) * 16 + n] = acc[j];
  }
  if (hB) {
    f32x4 acc = {0.f, 0.f, 0.f, 0.f};
#pragma unroll
    for (int kk = 0; kk < 4; ++kk) {
      float4 a0 = b[2 * kk], a1 = b[2 * kk + 1];
      bf16x8 A;
      A[0] = (short)f2bu(a0.x); A[1] = (short)f2bu(a0.y);
      A[2] = (short)f2bu(a0.z); A[3] = (short)f2bu(a0.w);
      A[4] = (short)f2bu(a1.x); A[5] = (short)f2bu(a1.y);
      A[6] = (short)f2bu(a1.z); A[7] = (short)f2bu(a1.w);
      acc = __builtin_amdgcn_mfma_f32_16x16x32_bf16(A, Bhi[kk], acc, 0, 0, 0);
      acc = __builtin_amdgcn_mfma_f32_16x16x32_bf16(A, Blo[kk], acc, 0, 0, 0);
    }
#pragma unroll
    for (int j = 0; j < 4; ++j)
      Dt[(size_t)(tB * 16 + q * 4 + j) * 16 + n] = acc[j];
  }
}

// ---------- lscat (+ optional one-hot block range) ----------
__global__ void __launch_bounds__(256) k_lscat(const int* __restrict__ story,
                                               const float* __restrict__ Dt,
                                               float* __restrict__ wt,
                                               float* __restrict__ ps,
                                               const float* __restrict__ pbv,
                                               const int* __restrict__ pbi,
                                               float* __restrict__ out) {
  const int bid = blockIdx.x, tid = threadIdx.x;
  if (bid < 128) {
    const int gt = bid * 256 + tid;            // 0..32767
    const int lane = tid & 63;
    const int b = gt >> 11, s = gt & 2047;
    int4 tk = ((const int4*)story)[b * SN + s];
    float l = Dt[(size_t)tk.x * 16 + b] + Dt[(size_t)tk.y * 16 + b]
            + Dt[(size_t)tk.z * 16 + b] + Dt[(size_t)tk.w * 16 + b];
    float e = expf(l);
    atomicAdd(&wt[(size_t)tk.x * 16 + b], e);
    atomicAdd(&wt[(size_t)tk.y * 16 + b], e);
    atomicAdd(&wt[(size_t)tk.z * 16 + b], e);
    atomicAdd(&wt[(size_t)tk.w * 16 + b], e);
    float sum = e;
#pragma unroll
    for (int off = 32; off > 0; off >>= 1) sum += __shfl_xor(sum, off, 64);
    if (lane == 0) ps[b * 32 + (s >> 6)] = sum;
  } else {
    int g = (bid - 128) * 256 + tid;
    if (g < 67232) {
      int head, b2, c; size_t off; int nch;
      if (g < 64000)      { head = 1; b2 = g / 4000; c = g % 4000; off = 64064 + g;          nch = 25; }
      else if (g < 67200) { int gg = g - 64000; head = 2; b2 = gg / 200; c = gg % 200; off = 131264 + gg; nch = 1; }
      else                { int gg = g - 67200; head = 0; b2 = gg >> 1; c = gg & 1;   off = 32 + gg;     nch = 1; }
      float bv = -INFINITY; int bi = 0x7FFFFFFF;
      for (int ch = 0; ch < nch; ++ch) {
        float v = pbv[(head * 16 + b2) * 25 + ch];
        int i2 = pbi[(head * 16 + b2) * 25 + ch];
        if (v > bv || (v == bv && i2 < bi)) { bv = v; bi = i2; }
      }
      out[off] = (c == bi) ? 1.0f : 0.0f;
    }
  }
}

// ---------- k_du: outer-product GEMV, depth-2 row pipeline, no atomics ----------
#define LOADR(CC, W0, W1, W2, W3, V) {                                   \
    CC = *(const float2*)(Ct + (size_t)(V) * EDIM + lane * 2);           \
    const float4* wp_ = (const float4*)(wt + (size_t)(V) * 16);          \
    W0 = wp_[0]; W1 = wp_[1]; W2 = wp_[2]; W3 = wp_[3]; }

#define FMAR(CC, W0, W1, W2, W3) {                                       \
    acc[0].x  += W0.x * CC.x; acc[0].y  += W0.x * CC.y;                  \
    acc[1].x  += W0.y * CC.x; acc[1].y  += W0.y * CC.y;                  \
    acc[2].x  += W0.z * CC.x; acc[2].y  += W0.z * CC.y;                  \
    acc[3].x  += W0.w * CC.x; acc[3].y  += W0.w * CC.y;                  \
    acc[4].x  += W1.x * CC.x; acc[4].y  += W1.x * CC.y;                  \
    acc[5].x  += W1.y * CC.x; acc[5].y  += W1.y * CC.y;                  \
    acc[6].x  += W1.z * CC.x; acc[6].y  += W1.z * CC.y;                  \
    acc[7].x  += W1.w * CC.x; acc[7].y  += W1.w * CC.y;                  \
    acc[8].x  += W2.x * CC.x; acc[8].y  += W2.x * CC.y;                  \
    acc[9].x  += W2.y * CC.x; acc[9].y  += W2.y * CC.y;                  \
    acc[10].x += W2.z * CC.x; acc[10].y += W2.z * CC.y;                  \
    acc[11].x += W2.w * CC.x; acc[11].y += W2.w * CC.y;                  \
    acc[12].x += W3.x * CC.x; acc[12].y += W3.x * CC.y;                  \
    acc[13].x += W3.y * CC.x; acc[13].y += W3.y * CC.y;                  \
    acc[14].x += W3.z * CC.x; acc[14].y += W3.z * CC.y;                  \
    acc[15].x += W3.w * CC.x; acc[15].y += W3.w * CC.y; }

__global__ void __launch_bounds__(256, 4) k_du(const float* __restrict__ Ct,
                                               const float* __restrict__ wt,
                                               float* __restrict__ dup) {
  const int tid = threadIdx.x, bid = blockIdx.x;
  const int lane = tid & 63, w = tid >> 6;
  __shared__ float lds[3 * 64 * 33];
  float2 acc[16];
#pragma unroll
  for (int b = 0; b < 16; ++b) acc[b] = make_float2(0.f, 0.f);
  const int r0 = bid * ROWS_PB + w * (ROWS_PB / 4);
  int rn = ROWS_PB / 4;                         // 49
  if (r0 + rn > VOCABN) rn = VOCABN - r0;       // may be <=0
  float2 ccA, ccB;
  float4 wA0, wA1, wA2, wA3, wB0, wB1, wB2, wB3;
  if (rn > 0) LOADR(ccA, wA0, wA1, wA2, wA3, r0);
  if (rn > 1) LOADR(ccB, wB0, wB1, wB2, wB3, r0 + 1);
  int r = 0;
  for (; r + 2 < rn; r += 2) {
    FMAR(ccA, wA0, wA1, wA2, wA3);
    LOADR(ccA, wA0, wA1, wA2, wA3, r0 + r + 2);
    FMAR(ccB, wB0, wB1, wB2, wB3);
    int rv = (r + 3 < rn) ? (r0 + r + 3) : (r0 + r);   // guard: dummy reload
    LOADR(ccB, wB0, wB1, wB2, wB3, rv);
  }
  if (r < rn)     { FMAR(ccA, wA0, wA1, wA2, wA3); }
  if (r + 1 < rn) { FMAR(ccB, wB0, wB1, wB2, wB3); }
  // cross-wave tree reduce in LDS (stride 17 float2 per lane: conflict-free)
  float2* L = (float2*)lds;
  if (w > 0) {
#pragma unroll
    for (int b = 0; b < 16; ++b) L[(w - 1) * 1088 + lane * 17 + b] = acc[b];
  }
  __syncthreads();
  if (w == 0) {
#pragma unroll
    for (int b = 0; b < 16; ++b) {
      float2 v0 = L[0 * 1088 + lane * 17 + b];
      float2 v1 = L[1 * 1088 + lane * 17 + b];
      float2 v2 = L[2 * 1088 + lane * 17 + b];
      acc[b].x += v0.x + v1.x + v2.x;
      acc[b].y += v0.y + v1.y + v2.y;
      *(float2*)(dup + (size_t)bid * 2048 + b * EDIM + lane * 2) = acc[b];
    }
  }
}

// ---------- k_red: u_next = u_prev + (sum_p dup[p]) / S_b  (32 blocks) ----------
__global__ void __launch_bounds__(256) k_red(const float* __restrict__ dup,
                                             const float* __restrict__ ps,
                                             const float* __restrict__ up,
                                             float* __restrict__ un) {
  const int tid = threadIdx.x, bid = blockIdx.x;
  const int l = tid & 63, chunk = tid >> 6;
  const int o = bid * 64 + l;                   // 0..2047
  float s = 0.f;
  for (int p = chunk * 128; p < chunk * 128 + 128; ++p)
    s += dup[(size_t)p * 2048 + o];
  __shared__ float L[4][64];
  L[chunk][l] = s;
  __syncthreads();
  if (chunk == 0) {
    float t = L[0][l] + L[1][l] + L[2][l] + L[3][l];
    const int b = o >> 7;
    float S = 0.f;
#pragma unroll
    for (int i = 0; i < 32; ++i) S += ps[b * 32 + i];
    un[o] = up[o] + t / S;
  }
}

// ---------- k_lfin: final logits -> masked sigmoid ----------
__global__ void __launch_bounds__(256) k_lfin(const int* __restrict__ story,
                                              const float* __restrict__ Dt,
                                              const int* __restrict__ lengths,
                                              float* __restrict__ out) {
  const int gt = blockIdx.x * 256 + threadIdx.x;   // grid 128 -> 32768
  const int b = gt >> 11, s = gt & 2047;
  int4 tk = ((const int4*)story)[b * SN + s];
  float l = Dt[(size_t)tk.x * 16 + b] + Dt[(size_t)tk.y * 16 + b]
          + Dt[(size_t)tk.z * 16 + b] + Dt[(size_t)tk.w * 16 + b];
  int len = lengths[b];
  out[134464 + (size_t)b * SN + s] = (s < len) ? 1.0f / (1.0f + expf(-l)) : 0.0f;
}

extern "C" void kernel_launch(void* const* d_in, const int* in_sizes, int n_in,
                              void* d_out, int out_size, void* d_ws, size_t ws_size,
                              hipStream_t stream) {
  const int *story = nullptr, *lengths = nullptr;
  const float *hidden = nullptr, *C = nullptr, *Wm = nullptr, *Wb = nullptr,
              *W1w = nullptr, *W1b = nullptr, *W3w = nullptr, *W3b = nullptr,
              *W4w = nullptr, *W4b = nullptr;
  for (int i = 0; i < n_in; ++i) {
    switch (in_sizes[i]) {
      case 16 * 2048 * 4:    story   = (const int*)d_in[i]; break;
      case 16:               lengths = (const int*)d_in[i]; break;
      case 16 * 128:         hidden  = (const float*)d_in[i]; break;
      case 4 * 100000 * 128: C       = (const float*)d_in[i]; break;
      case 128 * 128:        Wm      = (const float*)d_in[i]; break;
      case 128:              Wb      = (const float*)d_in[i]; break;
      case 2 * 128:          W1w     = (const float*)d_in[i]; break;
      case 2:                W1b     = (const float*)d_in[i]; break;
      case 4000 * 128:       W3w     = (const float*)d_in[i]; break;
      case 4000:             W3b     = (const float*)d_in[i]; break;
      case 200 * 128:        W4w     = (const float*)d_in[i]; break;
      case 200:              W4b     = (const float*)d_in[i]; break;
      default: break;
    }
  }
  float* out = (float*)d_out;
  float* ws  = (float*)d_ws;
  float* u0  = ws + U0_OFF;
  float* u1  = ws + U1_OFF;
  float* u2  = ws + U2_OFF;
  float* ps  = ws + PS_OFF;
  float* pbv = ws + PBV_OFF;
  int*   pbi = (int*)(ws + PBI_OFF);
  float* Dt  = ws + DT_OFF;
  float* wt  = ws + WT_OFF;
  float* dup = ws + DUP_OFF;

  const float* C0 = C;
  const float* C1 = C + (size_t)1 * VOCABN * EDIM;
  const float* C2 = C + (size_t)2 * VOCABN * EDIM;

  uint32_t k0a, k0b, k1a, k1b, k2a, k2b;
  tf2x32(0u, 42u, 0u, 0u, &k0a, &k0b);
  tf2x32(0u, 42u, 0u, 1u, &k1a, &k1b);
  tf2x32(0u, 42u, 0u, 2u, &k2a, &k2b);

  // heads (computes h in-block; persists u0)
  k_heads<<<432, 256, 0, stream>>>(hidden, Wm, Wb, W1w, W1b, W3w, W3b, W4w, W4b,
                                   out, pbv, pbi, u0,
                                   k0a, k0b, k1a, k1b, k2a, k2b);
  // hop 0
  k_D<<<NB_D, 256, 0, stream>>>(C0, u0, Dt, wt);
  k_lscat<<<391, 256, 0, stream>>>(story, Dt, wt, ps, pbv, pbi, out);  // + one-hots
  k_du<<<NB_DU, 256, 0, stream>>>(C1, wt, dup);
  k_red<<<32, 256, 0, stream>>>(dup, ps, u0, u1);
  // hop 1
  k_D<<<NB_D, 256, 0, stream>>>(C1, u1, Dt, wt);
  k_lscat<<<128, 256, 0, stream>>>(story, Dt, wt, ps, pbv, pbi, out);  // lscat only
  k_du<<<NB_DU, 256, 0, stream>>>(C2, wt, dup);
  k_red<<<32, 256, 0, stream>>>(dup, ps, u1, u2);
  // hop 2: final logits -> masked sigmoid
  k_D<<<NB_D, 256, 0, stream>>>(C2, u2, Dt, nullptr);
  k_lfin<<<128, 256, 0, stream>>>(story, Dt, lengths, out);
}